// Round 3
// baseline (1274.239 us; speedup 1.0000x reference)
//
#include <hip/hip_runtime.h>

// R11: R10 + amdgpu_waves_per_eu(4,4) pin on k_c2.
// R10 post-mortem: __launch_bounds__(1024,4) only sets the MIN waves/EU --
// the backend still TARGETED 8 waves/EU and kept VGPR_Count=64, spilling
// ~46 regs to scratch (WRITE_SIZE 126MB vs 61MB of real output). Occupancy
// is hard-capped at 4 waves/EU by 121.9KB LDS (1 WG/CU), so pinning
// waves_per_eu(4,4) raises the allocator budget to 128 VGPR and the ~114-reg
// live set fits with no scratch. No arithmetic change -> bit-identical.
//  - k_c2: 1024-thread blocks, conv tile 32x32 (pooled 16x16), 1 block/CU.
//    Input LDS layout [r][ic][cc pad 38] gives conflict-free ds_read_b64
//    column-pair loads (verified: SQ_LDS_BANK_CONFLICT 9.3e7 -> 1.16e6);
//    kx-rolling register reuse cuts input reads 6.7x. Each thread: one conv
//    row x col-pair x 16 oc; 2x2 pool via __shfl_xor(.,16) (fmaxf
//    order-invariant => exact). FMA chain strictly (ky,kx,ic) == R7/R8.
// NUMERICS CONTRACT (do not violate): golden is faithful float32 numpy;
// border-degenerate bilinear pixels flip discontinuously on ~1e-6 theta
// changes. Every conv/dense output must keep its exact sequential chain.
//
// ---- workspace (bytes), ~175MB ----
// th   f32[128*6]            @ 0
// h1   f32[128*120]          @ 4096
// p1   f32 NHWC [128][126][126][14] @ 65536      (113,799,168 B)
// part f32[311][128][120]    @ 65536  (19,107,840 B; overlaps p1: p1 is dead
//                                      before k_d1a writes part)
// p2   f32[128][119072]      @ 113930240         (60,964,864 B)
#define TH_OFF   0ull
#define H1_OFF   4096ull
#define P1_OFF   65536ull
#define PART_OFF 65536ull
#define P2_OFF   113930240ull

// ======= conv1 5x5 (1->14) + bias + relu + maxpool2, tiled =======
// block: 16x16 pool outputs, 1 batch; p1 NHWC [126][126][14]
__global__ __launch_bounds__(256) void k_c1(const float* __restrict__ x,
        const float* __restrict__ w1, const float* __restrict__ b1,
        float* __restrict__ p1)
{
    __shared__ float s_in[36*36];
    __shared__ float s_w[350];
    __shared__ float s_b[14];
    const int b   = blockIdx.z;
    const int ty0 = blockIdx.y * 16, tx0 = blockIdx.x * 16;
    const int tid = threadIdx.x;
    for (int i = tid; i < 36*36; i += 256) {
        int r = i / 36, c = i % 36;
        int gy = 2*ty0 + r, gx = 2*tx0 + c;
        float v = 0.f;
        if (gy < 256 && gx < 256) v = x[(long)(b*256 + gy)*256 + gx];
        s_in[i] = v;
    }
    for (int i = tid; i < 350; i += 256) s_w[i] = w1[i];
    if (tid < 14) s_b[tid] = b1[tid];
    __syncthreads();

    const int py = tid >> 4, px = tid & 15;
    float a0[14], a1[14], a2[14], a3[14];
    #pragma unroll
    for (int c = 0; c < 14; ++c) { a0[c]=0.f; a1[c]=0.f; a2[c]=0.f; a3[c]=0.f; }
    const int iy = 2*py, ix = 2*px;
    // chain order per accumulator: (ky,kx) sequential == R7
    #pragma unroll
    for (int ky = 0; ky < 5; ++ky) {
      #pragma unroll
      for (int kx = 0; kx < 5; ++kx) {
        float wv[14];
        #pragma unroll
        for (int c = 0; c < 14; ++c) wv[c] = s_w[(ky*5+kx)*14 + c];
        const float* ip = &s_in[(iy+ky)*36 + ix + kx];
        float v00 = ip[0],  v01 = ip[1];
        float v10 = ip[36], v11 = ip[37];
        #pragma unroll
        for (int c = 0; c < 14; ++c) {
            a0[c] = fmaf(v00, wv[c], a0[c]);
            a1[c] = fmaf(v01, wv[c], a1[c]);
            a2[c] = fmaf(v10, wv[c], a2[c]);
            a3[c] = fmaf(v11, wv[c], a3[c]);
        }
      }
    }
    const int oy = ty0 + py, ox = tx0 + px;
    if (oy < 126 && ox < 126) {
        float* op = &p1[((long)(b*126 + oy)*126 + ox)*14];
        #pragma unroll
        for (int c = 0; c < 14; ++c) {
            float bb = s_b[c];
            // R7 pool order: (0,0),(0,1),(1,0),(1,1)
            float m = fmaxf(__fadd_rn(a0[c], bb), 0.f);
            m = fmaxf(m, fmaxf(__fadd_rn(a1[c], bb), 0.f));
            m = fmaxf(m, fmaxf(__fadd_rn(a2[c], bb), 0.f));
            m = fmaxf(m, fmaxf(__fadd_rn(a3[c], bb), 0.f));
            op[c] = m;
        }
    }
}

// ======= conv2 5x5 (14->32) + bias + relu + maxpool2 (v2) =======
// block: 1024 thr = 512 pos (32 conv rows x 16 col-pairs) x 2 oc-groups(16).
// LDS: s_w 44.8KB + s_in[36][14][38] 76.6KB = 121.4KB -> 1 block/CU, 16 waves.
// s_in layout [r][ic][cc pad 38]: ds_read_b64 column pairs, conflict-free
// (16 lanes x 8B contiguous; row coeff 532 = 20 mod 32 spreads ppy groups).
// Per-output FMA chain (ky,kx,ic) sequential == R7/R8. Pool across partner
// row via shfl_xor(16); fmaxf is order-invariant => bit-exact.
// amdgpu_waves_per_eu(4,4): occupancy is LDS-capped at 4 waves/EU anyway;
// pinning max=4 gives the allocator a 128-VGPR budget (live set ~114),
// eliminating the 64-VGPR scratch spill seen in R9/R10.
#define C2_BLOCK(KX, VL, VR)                                        \
  { const int kb = (ky*5 + (KX))*14;                                \
    _Pragma("unroll")                                               \
    for (int ic = 0; ic < 14; ++ic) {                               \
      const float* wp = &s_w[(kb + ic)*32 + ocb];                   \
      float4 wA = *reinterpret_cast<const float4*>(wp);             \
      float4 wB = *reinterpret_cast<const float4*>(wp + 4);         \
      float4 wC = *reinterpret_cast<const float4*>(wp + 8);         \
      float4 wD = *reinterpret_cast<const float4*>(wp + 12);        \
      float wv[16] = {wA.x,wA.y,wA.z,wA.w, wB.x,wB.y,wB.z,wB.w,     \
                      wC.x,wC.y,wC.z,wC.w, wD.x,wD.y,wD.z,wD.w};    \
      float vl = (VL), vr = (VR);                                   \
      _Pragma("unroll")                                             \
      for (int c = 0; c < 16; ++c) {                                \
        accL[c] = fmaf(vl, wv[c], accL[c]);                         \
        accR[c] = fmaf(vr, wv[c], accR[c]);                         \
      } } }

__global__ __launch_bounds__(1024)
__attribute__((amdgpu_waves_per_eu(4, 4)))
void k_c2(const float* __restrict__ p1,
        const float* __restrict__ w2, const float* __restrict__ b2,
        float* __restrict__ p2)
{
    __shared__ float s_w[25*14*32];      // 44,800 B
    __shared__ float s_in[36*14*38];     // 76,608 B  [r][ic][cc pad38]
    const int b   = blockIdx.z;
    const int ty0 = blockIdx.y * 16, tx0 = blockIdx.x * 16;  // pooled origin
    const int tid = threadIdx.x;

    for (int i = tid; i < 11200; i += 1024) s_w[i] = w2[i];
    for (int i = tid; i < 36*36*14; i += 1024) {
        int ic = i % 14, rem = i / 14;
        int cc = rem % 36, r = rem / 36;
        int gy = 2*ty0 + r, gx = 2*tx0 + cc;
        float v = 0.f;
        if (gy < 126 && gx < 126) v = p1[((long)(b*126 + gy)*126 + gx)*14 + ic];
        s_in[(r*14 + ic)*38 + cc] = v;
    }
    __syncthreads();

    const int cg  = tid >> 9;            // 0..1, wave-uniform (bit 9)
    const int t   = tid & 511;
    const int py  = t >> 4;              // conv row in tile, 0..31
    const int ppx = t & 15;              // column pair, 0..15
    const int ocb = cg * 16;
    const int bx  = 2 * ppx;             // left conv col (even)

    float accL[16], accR[16];
    #pragma unroll
    for (int c = 0; c < 16; ++c) { accL[c] = 0.f; accR[c] = 0.f; }

    for (int ky = 0; ky < 5; ++ky) {
        const float* rp = &s_in[((py + ky)*14)*38 + bx];
        float2 X[14], Y[14];
        #pragma unroll
        for (int ic = 0; ic < 14; ++ic)
            X[ic] = *reinterpret_cast<const float2*>(rp + ic*38);      // cols bx,bx+1
        #pragma unroll
        for (int ic = 0; ic < 14; ++ic)
            Y[ic] = *reinterpret_cast<const float2*>(rp + ic*38 + 2);  // cols bx+2,bx+3
        C2_BLOCK(0, X[ic].x, X[ic].y)      // cols (bx+0, bx+1)
        C2_BLOCK(1, X[ic].y, Y[ic].x)      // cols (bx+1, bx+2)
        C2_BLOCK(2, Y[ic].x, Y[ic].y)      // cols (bx+2, bx+3)
        #pragma unroll
        for (int ic = 0; ic < 14; ++ic)
            X[ic] = *reinterpret_cast<const float2*>(rp + ic*38 + 4);  // cols bx+4,bx+5
        C2_BLOCK(3, Y[ic].y, X[ic].x)      // cols (bx+3, bx+4)
        C2_BLOCK(4, X[ic].x, X[ic].y)      // cols (bx+4, bx+5)
    }

    // pool: own row pair-of-cols + partner row (py^1 == lane^16, same wave).
    // R7 order (0,0),(0,1),(1,0),(1,1): max is order-invariant, bit-exact.
    const int prow = ty0 + (py >> 1);
    const int pcol = tx0 + ppx;
    const bool wr = ((py & 1) == 0) && prow < 61 && pcol < 61;
    float* op = &p2[(long)b*119072 + (long)(prow*61 + pcol)*32 + ocb];
    #pragma unroll
    for (int c = 0; c < 16; ++c) {
        float bb = b2[ocb + c];
        float m0 = fmaxf(__fadd_rn(accL[c], bb), 0.f);
        m0 = fmaxf(m0, fmaxf(__fadd_rn(accR[c], bb), 0.f));
        float m1 = __shfl_xor(m0, 16, 64);
        if (wr) op[c] = fmaxf(m0, m1);
    }
}

// ======= dense1 phase A: per-panel partials (bit-exact R7 panel chains) ====
// grid (311, 4): panel p, batch-group of 32. thread = column n.
// part[p][b][n] = sum_{k in panel p} p2[b][k]*w[k][n]  (sequential k FMA)
__global__ __launch_bounds__(128) void k_d1a(const float* __restrict__ p2,
        const float* __restrict__ w, float* __restrict__ part)
{
    const int n = threadIdx.x;
    const int panel = blockIdx.x;
    const int b0 = blockIdx.y * 32;
    if (n >= 120) return;
    const int kp = panel * 384;
    const int ke = (kp + 384 < 119072) ? kp + 384 : 119072;
    const float* a0 = p2 + (long)b0 * 119072;
    float p[32];
    #pragma unroll
    for (int i = 0; i < 32; ++i) p[i] = 0.f;
    for (int k = kp; k < ke; ++k) {
        float wv = w[(long)k * 120 + n];
        #pragma unroll
        for (int i = 0; i < 32; ++i)
            p[i] = fmaf(a0[(long)i * 119072 + k], wv, p[i]);
    }
    #pragma unroll
    for (int i = 0; i < 32; ++i)
        part[((long)panel * 128 + b0 + i) * 120 + n] = p[i];
}

// ======= dense1 phase B: in-order panel sum (== R7 h accumulation) =======
__global__ __launch_bounds__(128) void k_d1b(const float* __restrict__ part,
        float* __restrict__ h1)
{
    const int b = blockIdx.x, n = threadIdx.x;
    if (n >= 120) return;
    float h = 0.f;
    for (int p = 0; p < 311; ++p)
        h = __fadd_rn(h, part[((long)p * 128 + b) * 120 + n]);
    h1[b * 120 + n] = h;
}

// ======= head: relu(h1+b1) -> d2+relu -> d3+b -> theta, f32 seq-FMA =======
__global__ __launch_bounds__(128) void k_head(const float* __restrict__ h1,
        const float* __restrict__ d1b, const float* __restrict__ d2w,
        const float* __restrict__ d2b, const float* __restrict__ d3w,
        const float* __restrict__ d3b, float* __restrict__ theta)
{
    __shared__ float s1[120], s2[84];
    const int b = blockIdx.x, t = threadIdx.x;
    if (t < 120) s1[t] = fmaxf(__fadd_rn(h1[b * 120 + t], d1b[t]), 0.f);
    __syncthreads();
    if (t < 84) {
        float a = 0.f;
        for (int k = 0; k < 120; ++k) a = fmaf(s1[k], d2w[k * 84 + t], a);
        s2[t] = fmaxf(__fadd_rn(a, d2b[t]), 0.f);
    }
    __syncthreads();
    if (t < 6) {
        float a = 0.f;
        for (int k = 0; k < 84; ++k) a = fmaf(s2[k], d3w[k * 6 + t], a);
        theta[b * 6 + t] = __fadd_rn(a, d3b[t]);
    }
}

// ======= sampler: strict f32 reference expression tree (== R7) =======
__global__ __launch_bounds__(256) void k_sample(const float* __restrict__ x,
        const float* __restrict__ theta, const float* __restrict__ ow,
        const float* __restrict__ ob, float* __restrict__ out)
{
    const int idx = blockIdx.x * 256 + threadIdx.x;   // < 128*65536
    const int b   = idx >> 16;
    const int pix = idx & 65535;
    const int yy  = pix >> 8, xx = pix & 255;
    const float gx = __fadd_rn((float)xx * (1.f / 128.f), -1.f);
    const float gy = __fadd_rn((float)yy * (1.f / 128.f), -1.f);
    const float* th = &theta[b * 6];
    float rx = __fmul_rn(th[0], gx);
    rx = fmaf(th[1], gy, rx);
    rx = __fadd_rn(rx, th[2]);
    float ry = __fmul_rn(th[3], gx);
    ry = fmaf(th[4], gy, ry);
    ry = __fadd_rn(ry, th[5]);
    const float px = __fmul_rn(__fmul_rn(__fadd_rn(rx, 1.f), 0.5f), 256.f);
    const float py = __fmul_rn(__fmul_rn(__fadd_rn(ry, 1.f), 0.5f), 256.f);
    int x1 = (int)floorf(px), y1 = (int)floorf(py);
    int x2 = x1 + 1,  y2 = y1 + 1;
    x1 = min(max(x1, 0), 255); x2 = min(max(x2, 0), 255);
    y1 = min(max(y1, 0), 255); y2 = min(max(y2, 0), 255);
    const float* img = x + (long)b * 65536;
    const float p11 = img[y1 * 256 + x1];
    const float p12 = img[y2 * 256 + x1];
    const float p21 = img[y1 * 256 + x2];
    const float p22 = img[y2 * 256 + x2];
    const float wx1 = __fsub_rn((float)x2, px);
    const float wx2 = __fsub_rn(px, (float)x1);
    const float wy1 = __fsub_rn((float)y2, py);
    const float wy2 = __fsub_rn(py, (float)y1);
    const float sa = __fadd_rn(__fmul_rn(wy1, p11), __fmul_rn(wy2, p12));
    const float sb = __fadd_rn(__fmul_rn(wy1, p21), __fmul_rn(wy2, p22));
    const float r  = __fadd_rn(__fmul_rn(wx1, sa), __fmul_rn(wx2, sb));
    const float o  = __fadd_rn(__fmul_rn(r, ow[0]), ob[0]);
    out[idx] = 1.f / (1.f + expf(-o));
}

extern "C" void kernel_launch(void* const* d_in, const int* in_sizes, int n_in,
                              void* d_out, int out_size, void* d_ws, size_t ws_size,
                              hipStream_t stream)
{
    const float* x   = (const float*)d_in[0];
    const float* c1w = (const float*)d_in[1];
    const float* c1b = (const float*)d_in[2];
    const float* c2w = (const float*)d_in[3];
    const float* c2b = (const float*)d_in[4];
    const float* d1w = (const float*)d_in[5];
    const float* d1b = (const float*)d_in[6];
    const float* d2w = (const float*)d_in[7];
    const float* d2b = (const float*)d_in[8];
    const float* d3w = (const float*)d_in[9];
    const float* d3b = (const float*)d_in[10];
    const float* ow  = (const float*)d_in[11];
    const float* ob  = (const float*)d_in[12];

    char*  ws   = (char*)d_ws;
    float* th   = (float*)(ws + TH_OFF);
    float* h1   = (float*)(ws + H1_OFF);
    float* p1   = (float*)(ws + P1_OFF);
    float* part = (float*)(ws + PART_OFF);   // reuses p1 space (p1 dead)
    float* p2   = (float*)(ws + P2_OFF);

    k_c1    <<<dim3(8, 8, 128),  256,  0, stream>>>(x, c1w, c1b, p1);
    k_c2    <<<dim3(4, 4, 128),  1024, 0, stream>>>(p1, c2w, c2b, p2);
    k_d1a   <<<dim3(311, 4),     128,  0, stream>>>(p2, d1w, part);
    k_d1b   <<<dim3(128),        128,  0, stream>>>(part, h1);
    k_head  <<<dim3(128),        128,  0, stream>>>(h1, d1b, d2w, d2b, d3w, d3b, th);
    k_sample<<<dim3(32768),      256,  0, stream>>>(x, th, ow, ob, (float*)d_out);
}

// Round 4
// 1150.375 us; speedup vs baseline: 1.1077x; 1.1077x over previous
//
#include <hip/hip_runtime.h>

// R12: k_c2 weights moved OFF the LDS pipe (scalar/global path).
// R9-R11 post-mortem: VGPR_Count=64 is stable and spill traffic is ~31B/thread
// (one-time) -- spills were NOT the bottleneck. The real wall: 1400 weight
// ds_read_b128 broadcasts per wave on the shared per-CU LDS pipe (each feeds
// only 8 FMAs), ~3x the VALU's FMA cycles. Fix: ocb is wave-uniform (tid bit
// 9); anchor with readfirstlane and read weights straight from global w2 ->
// scalar s_load / L1-cached uniform loads (SMEM/VMEM pipes), zero LDS cost.
// Deleting s_w also drops LDS 121.4KB -> 76.6KB => 2 blocks/CU (8 waves/SIMD)
// and frees 16 weight VGPRs. Weight values bit-identical (s_w was a verbatim
// copy of w2); FMA chains untouched -> output bit-identical to R8-R11.
// NUMERICS CONTRACT (do not violate): golden is faithful float32 numpy;
// border-degenerate bilinear pixels flip discontinuously on ~1e-6 theta
// changes. Every conv/dense output must keep its exact sequential chain
// ((ky,kx) for conv1, (ky,kx,ic) for conv2, panel-k for dense1).
//
// ---- workspace (bytes), ~175MB ----
// th   f32[128*6]            @ 0
// h1   f32[128*120]          @ 4096
// p1   f32 NHWC [128][126][126][14] @ 65536      (113,799,168 B)
// part f32[311][128][120]    @ 65536  (19,107,840 B; overlaps p1: p1 is dead
//                                      before k_d1a writes part)
// p2   f32[128][119072]      @ 113930240         (60,964,864 B)
#define TH_OFF   0ull
#define H1_OFF   4096ull
#define P1_OFF   65536ull
#define PART_OFF 65536ull
#define P2_OFF   113930240ull

// ======= conv1 5x5 (1->14) + bias + relu + maxpool2, tiled =======
// block: 16x16 pool outputs, 1 batch; p1 NHWC [126][126][14]
__global__ __launch_bounds__(256) void k_c1(const float* __restrict__ x,
        const float* __restrict__ w1, const float* __restrict__ b1,
        float* __restrict__ p1)
{
    __shared__ float s_in[36*36];
    __shared__ float s_w[350];
    __shared__ float s_b[14];
    const int b   = blockIdx.z;
    const int ty0 = blockIdx.y * 16, tx0 = blockIdx.x * 16;
    const int tid = threadIdx.x;
    for (int i = tid; i < 36*36; i += 256) {
        int r = i / 36, c = i % 36;
        int gy = 2*ty0 + r, gx = 2*tx0 + c;
        float v = 0.f;
        if (gy < 256 && gx < 256) v = x[(long)(b*256 + gy)*256 + gx];
        s_in[i] = v;
    }
    for (int i = tid; i < 350; i += 256) s_w[i] = w1[i];
    if (tid < 14) s_b[tid] = b1[tid];
    __syncthreads();

    const int py = tid >> 4, px = tid & 15;
    float a0[14], a1[14], a2[14], a3[14];
    #pragma unroll
    for (int c = 0; c < 14; ++c) { a0[c]=0.f; a1[c]=0.f; a2[c]=0.f; a3[c]=0.f; }
    const int iy = 2*py, ix = 2*px;
    // chain order per accumulator: (ky,kx) sequential == R7
    #pragma unroll
    for (int ky = 0; ky < 5; ++ky) {
      #pragma unroll
      for (int kx = 0; kx < 5; ++kx) {
        float wv[14];
        #pragma unroll
        for (int c = 0; c < 14; ++c) wv[c] = s_w[(ky*5+kx)*14 + c];
        const float* ip = &s_in[(iy+ky)*36 + ix + kx];
        float v00 = ip[0],  v01 = ip[1];
        float v10 = ip[36], v11 = ip[37];
        #pragma unroll
        for (int c = 0; c < 14; ++c) {
            a0[c] = fmaf(v00, wv[c], a0[c]);
            a1[c] = fmaf(v01, wv[c], a1[c]);
            a2[c] = fmaf(v10, wv[c], a2[c]);
            a3[c] = fmaf(v11, wv[c], a3[c]);
        }
      }
    }
    const int oy = ty0 + py, ox = tx0 + px;
    if (oy < 126 && ox < 126) {
        float* op = &p1[((long)(b*126 + oy)*126 + ox)*14];
        #pragma unroll
        for (int c = 0; c < 14; ++c) {
            float bb = s_b[c];
            // R7 pool order: (0,0),(0,1),(1,0),(1,1)
            float m = fmaxf(__fadd_rn(a0[c], bb), 0.f);
            m = fmaxf(m, fmaxf(__fadd_rn(a1[c], bb), 0.f));
            m = fmaxf(m, fmaxf(__fadd_rn(a2[c], bb), 0.f));
            m = fmaxf(m, fmaxf(__fadd_rn(a3[c], bb), 0.f));
            op[c] = m;
        }
    }
}

// ======= conv2 5x5 (14->32) + bias + relu + maxpool2 (v3) =======
// block: 1024 thr = 512 pos (32 conv rows x 16 col-pairs) x 2 oc-groups(16).
// LDS: s_in[36][14][38] only, 76.6KB -> 2 blocks/CU (8 waves/SIMD).
// Weights: read from GLOBAL w2 at a readfirstlane-uniform address -> scalar
// s_load / L1-hit uniform loads; zero LDS-pipe cost (was 1400 b128/wave).
// s_in layout [r][ic][cc pad 38]: conflict-free ds_read_b64 column pairs.
// Per-output FMA chain (ky,kx,ic) sequential == R7/R8. Pool across partner
// row via shfl_xor(16); fmaxf is order-invariant => bit-exact.
#define C2_BLOCK(KX, VL, VR)                                        \
  { const int kb = (ky*5 + (KX))*14;                                \
    _Pragma("unroll")                                               \
    for (int ic = 0; ic < 14; ++ic) {                               \
      const float* wp = &w2[(kb + ic)*32 + ocb];                    \
      float4 wA = *reinterpret_cast<const float4*>(wp);             \
      float4 wB = *reinterpret_cast<const float4*>(wp + 4);         \
      float4 wC = *reinterpret_cast<const float4*>(wp + 8);         \
      float4 wD = *reinterpret_cast<const float4*>(wp + 12);        \
      float wv[16] = {wA.x,wA.y,wA.z,wA.w, wB.x,wB.y,wB.z,wB.w,     \
                      wC.x,wC.y,wC.z,wC.w, wD.x,wD.y,wD.z,wD.w};    \
      float vl = (VL), vr = (VR);                                   \
      _Pragma("unroll")                                             \
      for (int c = 0; c < 16; ++c) {                                \
        accL[c] = fmaf(vl, wv[c], accL[c]);                         \
        accR[c] = fmaf(vr, wv[c], accR[c]);                         \
      } } }

__global__ __launch_bounds__(1024) void k_c2(const float* __restrict__ p1,
        const float* __restrict__ w2, const float* __restrict__ b2,
        float* __restrict__ p2)
{
    __shared__ float s_in[36*14*38];     // 76,608 B  [r][ic][cc pad38]
    const int b   = blockIdx.z;
    const int ty0 = blockIdx.y * 16, tx0 = blockIdx.x * 16;  // pooled origin
    const int tid = threadIdx.x;

    for (int i = tid; i < 36*36*14; i += 1024) {
        int ic = i % 14, rem = i / 14;
        int cc = rem % 36, r = rem / 36;
        int gy = 2*ty0 + r, gx = 2*tx0 + cc;
        float v = 0.f;
        if (gy < 126 && gx < 126) v = p1[((long)(b*126 + gy)*126 + gx)*14 + ic];
        s_in[(r*14 + ic)*38 + cc] = v;
    }
    __syncthreads();

    // cg (tid bit 9) is uniform within each 64-lane wave; readfirstlane makes
    // that provable -> weight addresses become scalar (s_load path).
    const int cg  = __builtin_amdgcn_readfirstlane(tid >> 9);  // 0..1
    const int t   = tid & 511;
    const int py  = t >> 4;              // conv row in tile, 0..31
    const int ppx = t & 15;              // column pair, 0..15
    const int ocb = cg * 16;
    const int bx  = 2 * ppx;             // left conv col (even)

    float accL[16], accR[16];
    #pragma unroll
    for (int c = 0; c < 16; ++c) { accL[c] = 0.f; accR[c] = 0.f; }

    for (int ky = 0; ky < 5; ++ky) {
        const float* rp = &s_in[((py + ky)*14)*38 + bx];
        float2 X[14], Y[14];
        #pragma unroll
        for (int ic = 0; ic < 14; ++ic)
            X[ic] = *reinterpret_cast<const float2*>(rp + ic*38);      // cols bx,bx+1
        #pragma unroll
        for (int ic = 0; ic < 14; ++ic)
            Y[ic] = *reinterpret_cast<const float2*>(rp + ic*38 + 2);  // cols bx+2,bx+3
        C2_BLOCK(0, X[ic].x, X[ic].y)      // cols (bx+0, bx+1)
        C2_BLOCK(1, X[ic].y, Y[ic].x)      // cols (bx+1, bx+2)
        C2_BLOCK(2, Y[ic].x, Y[ic].y)      // cols (bx+2, bx+3)
        #pragma unroll
        for (int ic = 0; ic < 14; ++ic)
            X[ic] = *reinterpret_cast<const float2*>(rp + ic*38 + 4);  // cols bx+4,bx+5
        C2_BLOCK(3, Y[ic].y, X[ic].x)      // cols (bx+3, bx+4)
        C2_BLOCK(4, X[ic].x, X[ic].y)      // cols (bx+4, bx+5)
    }

    // pool: own row pair-of-cols + partner row (py^1 == lane^16, same wave).
    // R7 order (0,0),(0,1),(1,0),(1,1): max is order-invariant, bit-exact.
    const int prow = ty0 + (py >> 1);
    const int pcol = tx0 + ppx;
    const bool wr = ((py & 1) == 0) && prow < 61 && pcol < 61;
    float* op = &p2[(long)b*119072 + (long)(prow*61 + pcol)*32 + ocb];
    #pragma unroll
    for (int c = 0; c < 16; ++c) {
        float bb = b2[ocb + c];
        float m0 = fmaxf(__fadd_rn(accL[c], bb), 0.f);
        m0 = fmaxf(m0, fmaxf(__fadd_rn(accR[c], bb), 0.f));
        float m1 = __shfl_xor(m0, 16, 64);
        if (wr) op[c] = fmaxf(m0, m1);
    }
}

// ======= dense1 phase A: per-panel partials (bit-exact R7 panel chains) ====
// grid (311, 4): panel p, batch-group of 32. thread = column n.
// part[p][b][n] = sum_{k in panel p} p2[b][k]*w[k][n]  (sequential k FMA)
__global__ __launch_bounds__(128) void k_d1a(const float* __restrict__ p2,
        const float* __restrict__ w, float* __restrict__ part)
{
    const int n = threadIdx.x;
    const int panel = blockIdx.x;
    const int b0 = blockIdx.y * 32;
    if (n >= 120) return;
    const int kp = panel * 384;
    const int ke = (kp + 384 < 119072) ? kp + 384 : 119072;
    const float* a0 = p2 + (long)b0 * 119072;
    float p[32];
    #pragma unroll
    for (int i = 0; i < 32; ++i) p[i] = 0.f;
    for (int k = kp; k < ke; ++k) {
        float wv = w[(long)k * 120 + n];
        #pragma unroll
        for (int i = 0; i < 32; ++i)
            p[i] = fmaf(a0[(long)i * 119072 + k], wv, p[i]);
    }
    #pragma unroll
    for (int i = 0; i < 32; ++i)
        part[((long)panel * 128 + b0 + i) * 120 + n] = p[i];
}

// ======= dense1 phase B: in-order panel sum (== R7 h accumulation) =======
__global__ __launch_bounds__(128) void k_d1b(const float* __restrict__ part,
        float* __restrict__ h1)
{
    const int b = blockIdx.x, n = threadIdx.x;
    if (n >= 120) return;
    float h = 0.f;
    for (int p = 0; p < 311; ++p)
        h = __fadd_rn(h, part[((long)p * 128 + b) * 120 + n]);
    h1[b * 120 + n] = h;
}

// ======= head: relu(h1+b1) -> d2+relu -> d3+b -> theta, f32 seq-FMA =======
__global__ __launch_bounds__(128) void k_head(const float* __restrict__ h1,
        const float* __restrict__ d1b, const float* __restrict__ d2w,
        const float* __restrict__ d2b, const float* __restrict__ d3w,
        const float* __restrict__ d3b, float* __restrict__ theta)
{
    __shared__ float s1[120], s2[84];
    const int b = blockIdx.x, t = threadIdx.x;
    if (t < 120) s1[t] = fmaxf(__fadd_rn(h1[b * 120 + t], d1b[t]), 0.f);
    __syncthreads();
    if (t < 84) {
        float a = 0.f;
        for (int k = 0; k < 120; ++k) a = fmaf(s1[k], d2w[k * 84 + t], a);
        s2[t] = fmaxf(__fadd_rn(a, d2b[t]), 0.f);
    }
    __syncthreads();
    if (t < 6) {
        float a = 0.f;
        for (int k = 0; k < 84; ++k) a = fmaf(s2[k], d3w[k * 6 + t], a);
        theta[b * 6 + t] = __fadd_rn(a, d3b[t]);
    }
}

// ======= sampler: strict f32 reference expression tree (== R7) =======
__global__ __launch_bounds__(256) void k_sample(const float* __restrict__ x,
        const float* __restrict__ theta, const float* __restrict__ ow,
        const float* __restrict__ ob, float* __restrict__ out)
{
    const int idx = blockIdx.x * 256 + threadIdx.x;   // < 128*65536
    const int b   = idx >> 16;
    const int pix = idx & 65535;
    const int yy  = pix >> 8, xx = pix & 255;
    const float gx = __fadd_rn((float)xx * (1.f / 128.f), -1.f);
    const float gy = __fadd_rn((float)yy * (1.f / 128.f), -1.f);
    const float* th = &theta[b * 6];
    float rx = __fmul_rn(th[0], gx);
    rx = fmaf(th[1], gy, rx);
    rx = __fadd_rn(rx, th[2]);
    float ry = __fmul_rn(th[3], gx);
    ry = fmaf(th[4], gy, ry);
    ry = __fadd_rn(ry, th[5]);
    const float px = __fmul_rn(__fmul_rn(__fadd_rn(rx, 1.f), 0.5f), 256.f);
    const float py = __fmul_rn(__fmul_rn(__fadd_rn(ry, 1.f), 0.5f), 256.f);
    int x1 = (int)floorf(px), y1 = (int)floorf(py);
    int x2 = x1 + 1,  y2 = y1 + 1;
    x1 = min(max(x1, 0), 255); x2 = min(max(x2, 0), 255);
    y1 = min(max(y1, 0), 255); y2 = min(max(y2, 0), 255);
    const float* img = x + (long)b * 65536;
    const float p11 = img[y1 * 256 + x1];
    const float p12 = img[y2 * 256 + x1];
    const float p21 = img[y1 * 256 + x2];
    const float p22 = img[y2 * 256 + x2];
    const float wx1 = __fsub_rn((float)x2, px);
    const float wx2 = __fsub_rn(px, (float)x1);
    const float wy1 = __fsub_rn((float)y2, py);
    const float wy2 = __fsub_rn(py, (float)y1);
    const float sa = __fadd_rn(__fmul_rn(wy1, p11), __fmul_rn(wy2, p12));
    const float sb = __fadd_rn(__fmul_rn(wy1, p21), __fmul_rn(wy2, p22));
    const float r  = __fadd_rn(__fmul_rn(wx1, sa), __fmul_rn(wx2, sb));
    const float o  = __fadd_rn(__fmul_rn(r, ow[0]), ob[0]);
    out[idx] = 1.f / (1.f + expf(-o));
}

extern "C" void kernel_launch(void* const* d_in, const int* in_sizes, int n_in,
                              void* d_out, int out_size, void* d_ws, size_t ws_size,
                              hipStream_t stream)
{
    const float* x   = (const float*)d_in[0];
    const float* c1w = (const float*)d_in[1];
    const float* c1b = (const float*)d_in[2];
    const float* c2w = (const float*)d_in[3];
    const float* c2b = (const float*)d_in[4];
    const float* d1w = (const float*)d_in[5];
    const float* d1b = (const float*)d_in[6];
    const float* d2w = (const float*)d_in[7];
    const float* d2b = (const float*)d_in[8];
    const float* d3w = (const float*)d_in[9];
    const float* d3b = (const float*)d_in[10];
    const float* ow  = (const float*)d_in[11];
    const float* ob  = (const float*)d_in[12];

    char*  ws   = (char*)d_ws;
    float* th   = (float*)(ws + TH_OFF);
    float* h1   = (float*)(ws + H1_OFF);
    float* p1   = (float*)(ws + P1_OFF);
    float* part = (float*)(ws + PART_OFF);   // reuses p1 space (p1 dead)
    float* p2   = (float*)(ws + P2_OFF);

    k_c1    <<<dim3(8, 8, 128),  256,  0, stream>>>(x, c1w, c1b, p1);
    k_c2    <<<dim3(4, 4, 128),  1024, 0, stream>>>(p1, c2w, c2b, p2);
    k_d1a   <<<dim3(311, 4),     128,  0, stream>>>(p2, d1w, part);
    k_d1b   <<<dim3(128),        128,  0, stream>>>(part, h1);
    k_head  <<<dim3(128),        128,  0, stream>>>(h1, d1b, d2w, d2b, d3w, d3b, th);
    k_sample<<<dim3(32768),      256,  0, stream>>>(x, th, ow, ob, (float*)d_out);
}

// Round 5
// 1146.128 us; speedup vs baseline: 1.1118x; 1.0037x over previous
//
#include <hip/hip_runtime.h>

// R13: k_c2 tile split 32->16 conv rows; inner loop byte-identical to R12.
// R12 post-mortem: weights->scalar path WORKED (558us, WRITE back to 61MB,
// VGPR 48, VALUBusy 70.5%). Remaining 30% issue-idle correlates with
// OccupancyPercent=41% (~13 waves/CU) despite LDS/VGPR permitting 32: the
// 1024-thread blocks pack badly (~1.3 resident/CU, 16-wave barrier cohorts).
// Fix: 512-thread blocks over 16 conv rows, s_in[20][14][38]=42.6KB ->
// 3 blocks/CU = 24 waves/CU = 6 waves/SIMD to hide the per-ic s_load stall.
// Per-thread arithmetic, chain order, LDS layout, weight path unchanged ->
// output bit-identical to R8-R12 (PASSED, absmax 0.00390625).
// NUMERICS CONTRACT (do not violate): golden is faithful float32 numpy;
// border-degenerate bilinear pixels flip discontinuously on ~1e-6 theta
// changes. Every conv/dense output must keep its exact sequential chain
// ((ky,kx) for conv1, (ky,kx,ic) for conv2, panel-k for dense1).
//
// ---- workspace (bytes), ~175MB ----
// th   f32[128*6]            @ 0
// h1   f32[128*120]          @ 4096
// p1   f32 NHWC [128][126][126][14] @ 65536      (113,799,168 B)
// part f32[311][128][120]    @ 65536  (19,107,840 B; overlaps p1: p1 is dead
//                                      before k_d1a writes part)
// p2   f32[128][119072]      @ 113930240         (60,964,864 B)
#define TH_OFF   0ull
#define H1_OFF   4096ull
#define P1_OFF   65536ull
#define PART_OFF 65536ull
#define P2_OFF   113930240ull

// ======= conv1 5x5 (1->14) + bias + relu + maxpool2, tiled =======
// block: 16x16 pool outputs, 1 batch; p1 NHWC [126][126][14]
__global__ __launch_bounds__(256) void k_c1(const float* __restrict__ x,
        const float* __restrict__ w1, const float* __restrict__ b1,
        float* __restrict__ p1)
{
    __shared__ float s_in[36*36];
    __shared__ float s_w[350];
    __shared__ float s_b[14];
    const int b   = blockIdx.z;
    const int ty0 = blockIdx.y * 16, tx0 = blockIdx.x * 16;
    const int tid = threadIdx.x;
    for (int i = tid; i < 36*36; i += 256) {
        int r = i / 36, c = i % 36;
        int gy = 2*ty0 + r, gx = 2*tx0 + c;
        float v = 0.f;
        if (gy < 256 && gx < 256) v = x[(long)(b*256 + gy)*256 + gx];
        s_in[i] = v;
    }
    for (int i = tid; i < 350; i += 256) s_w[i] = w1[i];
    if (tid < 14) s_b[tid] = b1[tid];
    __syncthreads();

    const int py = tid >> 4, px = tid & 15;
    float a0[14], a1[14], a2[14], a3[14];
    #pragma unroll
    for (int c = 0; c < 14; ++c) { a0[c]=0.f; a1[c]=0.f; a2[c]=0.f; a3[c]=0.f; }
    const int iy = 2*py, ix = 2*px;
    // chain order per accumulator: (ky,kx) sequential == R7
    #pragma unroll
    for (int ky = 0; ky < 5; ++ky) {
      #pragma unroll
      for (int kx = 0; kx < 5; ++kx) {
        float wv[14];
        #pragma unroll
        for (int c = 0; c < 14; ++c) wv[c] = s_w[(ky*5+kx)*14 + c];
        const float* ip = &s_in[(iy+ky)*36 + ix + kx];
        float v00 = ip[0],  v01 = ip[1];
        float v10 = ip[36], v11 = ip[37];
        #pragma unroll
        for (int c = 0; c < 14; ++c) {
            a0[c] = fmaf(v00, wv[c], a0[c]);
            a1[c] = fmaf(v01, wv[c], a1[c]);
            a2[c] = fmaf(v10, wv[c], a2[c]);
            a3[c] = fmaf(v11, wv[c], a3[c]);
        }
      }
    }
    const int oy = ty0 + py, ox = tx0 + px;
    if (oy < 126 && ox < 126) {
        float* op = &p1[((long)(b*126 + oy)*126 + ox)*14];
        #pragma unroll
        for (int c = 0; c < 14; ++c) {
            float bb = s_b[c];
            // R7 pool order: (0,0),(0,1),(1,0),(1,1)
            float m = fmaxf(__fadd_rn(a0[c], bb), 0.f);
            m = fmaxf(m, fmaxf(__fadd_rn(a1[c], bb), 0.f));
            m = fmaxf(m, fmaxf(__fadd_rn(a2[c], bb), 0.f));
            m = fmaxf(m, fmaxf(__fadd_rn(a3[c], bb), 0.f));
            op[c] = m;
        }
    }
}

// ======= conv2 5x5 (14->32) + bias + relu + maxpool2 (v4) =======
// block: 512 thr = 256 pos (16 conv rows x 16 col-pairs) x 2 oc-groups(16).
// LDS: s_in[20][14][38] = 42,560 B -> 3 blocks/CU (24 waves/CU, 6/SIMD).
// Weights: read from GLOBAL w2 at a readfirstlane-uniform address -> scalar
// s_load / L1-hit uniform loads; zero LDS-pipe cost.
// s_in layout [r][ic][cc pad 38]: conflict-free ds_read_b64 column pairs.
// Per-output FMA chain (ky,kx,ic) sequential == R7/R8. Pool across partner
// row via shfl_xor(16); fmaxf is order-invariant => bit-exact.
#define C2_BLOCK(KX, VL, VR)                                        \
  { const int kb = (ky*5 + (KX))*14;                                \
    _Pragma("unroll")                                               \
    for (int ic = 0; ic < 14; ++ic) {                               \
      const float* wp = &w2[(kb + ic)*32 + ocb];                    \
      float4 wA = *reinterpret_cast<const float4*>(wp);             \
      float4 wB = *reinterpret_cast<const float4*>(wp + 4);         \
      float4 wC = *reinterpret_cast<const float4*>(wp + 8);         \
      float4 wD = *reinterpret_cast<const float4*>(wp + 12);        \
      float wv[16] = {wA.x,wA.y,wA.z,wA.w, wB.x,wB.y,wB.z,wB.w,     \
                      wC.x,wC.y,wC.z,wC.w, wD.x,wD.y,wD.z,wD.w};    \
      float vl = (VL), vr = (VR);                                   \
      _Pragma("unroll")                                             \
      for (int c = 0; c < 16; ++c) {                                \
        accL[c] = fmaf(vl, wv[c], accL[c]);                         \
        accR[c] = fmaf(vr, wv[c], accR[c]);                         \
      } } }

__global__ __launch_bounds__(512) void k_c2(const float* __restrict__ p1,
        const float* __restrict__ w2, const float* __restrict__ b2,
        float* __restrict__ p2)
{
    __shared__ float s_in[20*14*38];     // 42,560 B  [r 0..19][ic][cc pad38]
    const int b   = blockIdx.z;
    const int ty0 = blockIdx.y * 8, tx0 = blockIdx.x * 16;   // pooled origin
    const int tid = threadIdx.x;

    // stage 20 input rows x 36 cols x 14 ic (conv rows 16*by .. +15 need
    // input rows 16*by .. +19)
    for (int i = tid; i < 20*36*14; i += 512) {
        int ic = i % 14, rem = i / 14;
        int cc = rem % 36, r = rem / 36;
        int gy = 2*ty0 + r, gx = 2*tx0 + cc;
        float v = 0.f;
        if (gy < 126 && gx < 126) v = p1[((long)(b*126 + gy)*126 + gx)*14 + ic];
        s_in[(r*14 + ic)*38 + cc] = v;
    }
    __syncthreads();

    // cg (tid bit 8) is uniform within each 64-lane wave; readfirstlane makes
    // that provable -> weight addresses become scalar (s_load path).
    const int cg  = __builtin_amdgcn_readfirstlane(tid >> 8);  // 0..1
    const int t   = tid & 255;
    const int py  = t >> 4;              // conv row in tile, 0..15
    const int ppx = t & 15;              // column pair, 0..15
    const int ocb = cg * 16;
    const int bx  = 2 * ppx;             // left conv col (even)

    float accL[16], accR[16];
    #pragma unroll
    for (int c = 0; c < 16; ++c) { accL[c] = 0.f; accR[c] = 0.f; }

    for (int ky = 0; ky < 5; ++ky) {
        const float* rp = &s_in[((py + ky)*14)*38 + bx];
        float2 X[14], Y[14];
        #pragma unroll
        for (int ic = 0; ic < 14; ++ic)
            X[ic] = *reinterpret_cast<const float2*>(rp + ic*38);      // cols bx,bx+1
        #pragma unroll
        for (int ic = 0; ic < 14; ++ic)
            Y[ic] = *reinterpret_cast<const float2*>(rp + ic*38 + 2);  // cols bx+2,bx+3
        C2_BLOCK(0, X[ic].x, X[ic].y)      // cols (bx+0, bx+1)
        C2_BLOCK(1, X[ic].y, Y[ic].x)      // cols (bx+1, bx+2)
        C2_BLOCK(2, Y[ic].x, Y[ic].y)      // cols (bx+2, bx+3)
        #pragma unroll
        for (int ic = 0; ic < 14; ++ic)
            X[ic] = *reinterpret_cast<const float2*>(rp + ic*38 + 4);  // cols bx+4,bx+5
        C2_BLOCK(3, Y[ic].y, X[ic].x)      // cols (bx+3, bx+4)
        C2_BLOCK(4, X[ic].x, X[ic].y)      // cols (bx+4, bx+5)
    }

    // pool: own row pair-of-cols + partner row (py^1 == lane^16, same wave).
    // R7 order (0,0),(0,1),(1,0),(1,1): max is order-invariant, bit-exact.
    const int prow = ty0 + (py >> 1);
    const int pcol = tx0 + ppx;
    const bool wr = ((py & 1) == 0) && prow < 61 && pcol < 61;
    float* op = &p2[(long)b*119072 + (long)(prow*61 + pcol)*32 + ocb];
    #pragma unroll
    for (int c = 0; c < 16; ++c) {
        float bb = b2[ocb + c];
        float m0 = fmaxf(__fadd_rn(accL[c], bb), 0.f);
        m0 = fmaxf(m0, fmaxf(__fadd_rn(accR[c], bb), 0.f));
        float m1 = __shfl_xor(m0, 16, 64);
        if (wr) op[c] = fmaxf(m0, m1);
    }
}

// ======= dense1 phase A: per-panel partials (bit-exact R7 panel chains) ====
// grid (311, 4): panel p, batch-group of 32. thread = column n.
// part[p][b][n] = sum_{k in panel p} p2[b][k]*w[k][n]  (sequential k FMA)
__global__ __launch_bounds__(128) void k_d1a(const float* __restrict__ p2,
        const float* __restrict__ w, float* __restrict__ part)
{
    const int n = threadIdx.x;
    const int panel = blockIdx.x;
    const int b0 = blockIdx.y * 32;
    if (n >= 120) return;
    const int kp = panel * 384;
    const int ke = (kp + 384 < 119072) ? kp + 384 : 119072;
    const float* a0 = p2 + (long)b0 * 119072;
    float p[32];
    #pragma unroll
    for (int i = 0; i < 32; ++i) p[i] = 0.f;
    for (int k = kp; k < ke; ++k) {
        float wv = w[(long)k * 120 + n];
        #pragma unroll
        for (int i = 0; i < 32; ++i)
            p[i] = fmaf(a0[(long)i * 119072 + k], wv, p[i]);
    }
    #pragma unroll
    for (int i = 0; i < 32; ++i)
        part[((long)panel * 128 + b0 + i) * 120 + n] = p[i];
}

// ======= dense1 phase B: in-order panel sum (== R7 h accumulation) =======
__global__ __launch_bounds__(128) void k_d1b(const float* __restrict__ part,
        float* __restrict__ h1)
{
    const int b = blockIdx.x, n = threadIdx.x;
    if (n >= 120) return;
    float h = 0.f;
    for (int p = 0; p < 311; ++p)
        h = __fadd_rn(h, part[((long)p * 128 + b) * 120 + n]);
    h1[b * 120 + n] = h;
}

// ======= head: relu(h1+b1) -> d2+relu -> d3+b -> theta, f32 seq-FMA =======
__global__ __launch_bounds__(128) void k_head(const float* __restrict__ h1,
        const float* __restrict__ d1b, const float* __restrict__ d2w,
        const float* __restrict__ d2b, const float* __restrict__ d3w,
        const float* __restrict__ d3b, float* __restrict__ theta)
{
    __shared__ float s1[120], s2[84];
    const int b = blockIdx.x, t = threadIdx.x;
    if (t < 120) s1[t] = fmaxf(__fadd_rn(h1[b * 120 + t], d1b[t]), 0.f);
    __syncthreads();
    if (t < 84) {
        float a = 0.f;
        for (int k = 0; k < 120; ++k) a = fmaf(s1[k], d2w[k * 84 + t], a);
        s2[t] = fmaxf(__fadd_rn(a, d2b[t]), 0.f);
    }
    __syncthreads();
    if (t < 6) {
        float a = 0.f;
        for (int k = 0; k < 84; ++k) a = fmaf(s2[k], d3w[k * 6 + t], a);
        theta[b * 6 + t] = __fadd_rn(a, d3b[t]);
    }
}

// ======= sampler: strict f32 reference expression tree (== R7) =======
__global__ __launch_bounds__(256) void k_sample(const float* __restrict__ x,
        const float* __restrict__ theta, const float* __restrict__ ow,
        const float* __restrict__ ob, float* __restrict__ out)
{
    const int idx = blockIdx.x * 256 + threadIdx.x;   // < 128*65536
    const int b   = idx >> 16;
    const int pix = idx & 65535;
    const int yy  = pix >> 8, xx = pix & 255;
    const float gx = __fadd_rn((float)xx * (1.f / 128.f), -1.f);
    const float gy = __fadd_rn((float)yy * (1.f / 128.f), -1.f);
    const float* th = &theta[b * 6];
    float rx = __fmul_rn(th[0], gx);
    rx = fmaf(th[1], gy, rx);
    rx = __fadd_rn(rx, th[2]);
    float ry = __fmul_rn(th[3], gx);
    ry = fmaf(th[4], gy, ry);
    ry = __fadd_rn(ry, th[5]);
    const float px = __fmul_rn(__fmul_rn(__fadd_rn(rx, 1.f), 0.5f), 256.f);
    const float py = __fmul_rn(__fmul_rn(__fadd_rn(ry, 1.f), 0.5f), 256.f);
    int x1 = (int)floorf(px), y1 = (int)floorf(py);
    int x2 = x1 + 1,  y2 = y1 + 1;
    x1 = min(max(x1, 0), 255); x2 = min(max(x2, 0), 255);
    y1 = min(max(y1, 0), 255); y2 = min(max(y2, 0), 255);
    const float* img = x + (long)b * 65536;
    const float p11 = img[y1 * 256 + x1];
    const float p12 = img[y2 * 256 + x1];
    const float p21 = img[y1 * 256 + x2];
    const float p22 = img[y2 * 256 + x2];
    const float wx1 = __fsub_rn((float)x2, px);
    const float wx2 = __fsub_rn(px, (float)x1);
    const float wy1 = __fsub_rn((float)y2, py);
    const float wy2 = __fsub_rn(py, (float)y1);
    const float sa = __fadd_rn(__fmul_rn(wy1, p11), __fmul_rn(wy2, p12));
    const float sb = __fadd_rn(__fmul_rn(wy1, p21), __fmul_rn(wy2, p22));
    const float r  = __fadd_rn(__fmul_rn(wx1, sa), __fmul_rn(wx2, sb));
    const float o  = __fadd_rn(__fmul_rn(r, ow[0]), ob[0]);
    out[idx] = 1.f / (1.f + expf(-o));
}

extern "C" void kernel_launch(void* const* d_in, const int* in_sizes, int n_in,
                              void* d_out, int out_size, void* d_ws, size_t ws_size,
                              hipStream_t stream)
{
    const float* x   = (const float*)d_in[0];
    const float* c1w = (const float*)d_in[1];
    const float* c1b = (const float*)d_in[2];
    const float* c2w = (const float*)d_in[3];
    const float* c2b = (const float*)d_in[4];
    const float* d1w = (const float*)d_in[5];
    const float* d1b = (const float*)d_in[6];
    const float* d2w = (const float*)d_in[7];
    const float* d2b = (const float*)d_in[8];
    const float* d3w = (const float*)d_in[9];
    const float* d3b = (const float*)d_in[10];
    const float* ow  = (const float*)d_in[11];
    const float* ob  = (const float*)d_in[12];

    char*  ws   = (char*)d_ws;
    float* th   = (float*)(ws + TH_OFF);
    float* h1   = (float*)(ws + H1_OFF);
    float* p1   = (float*)(ws + P1_OFF);
    float* part = (float*)(ws + PART_OFF);   // reuses p1 space (p1 dead)
    float* p2   = (float*)(ws + P2_OFF);

    k_c1    <<<dim3(8, 8, 128),  256, 0, stream>>>(x, c1w, c1b, p1);
    k_c2    <<<dim3(4, 8, 128),  512, 0, stream>>>(p1, c2w, c2b, p2);
    k_d1a   <<<dim3(311, 4),     128, 0, stream>>>(p2, d1w, part);
    k_d1b   <<<dim3(128),        128, 0, stream>>>(part, h1);
    k_head  <<<dim3(128),        128, 0, stream>>>(h1, d1b, d2w, d2b, d3w, d3b, th);
    k_sample<<<dim3(32768),      256, 0, stream>>>(x, th, ow, ob, (float*)d_out);
}